// Round 7
// baseline (10087.948 us; speedup 1.0000x reference)
//
#include <hip/hip_runtime.h>
#include <cstdint>
#include <cstddef>

// GRU: T=512, B=64, I=256, H=1024, O=256, L=3
#define TT 512
#define BB 64
#define II 256
#define HH 1024
#define OO 256
#define LL 3
#define NBLK 192
#define TSLOTS 513            // T+1 state slots per layer
#define SSTEPS (TT + 5)       // 517 supersteps (depth-2 layer pipeline)
// LDS layout (bytes)
#define LDS_GI   98304                 // after 96KB whh frags
#define GI_STRIDE 68                   // floats, padded
#define LDS_HT   (LDS_GI + 26112)      // gi = 2*3*16*68*4 = 26112
#define LDS_TOTAL (LDS_HT + 2048)      // + ht 64*16*2 = 126464

typedef _Float16 half8 __attribute__((ext_vector_type(8)));
typedef float floatx4 __attribute__((ext_vector_type(4)));
typedef float float4v __attribute__((ext_vector_type(4)));

__device__ __forceinline__ floatx4 mfma16(half8 a, half8 b, floatx4 c) {
    return __builtin_amdgcn_mfma_f32_16x16x32_f16(a, b, c, 0, 0, 0);
}

// fast transcendentals: v_exp_f32 + v_rcp_f32 (~1ulp, fine vs fp16 noise)
__device__ __forceinline__ float fast_sig(float x) {
    return __builtin_amdgcn_rcpf(1.f + __builtin_amdgcn_exp2f(-1.44269504f * x));
}
__device__ __forceinline__ float fast_tanh(float x) {
    return 1.f - 2.f * __builtin_amdgcn_rcpf(1.f + __builtin_amdgcn_exp2f(2.88539008f * x));
}

__device__ __forceinline__ half8 ld_f32x8_cvt(const float* p) {
    float4v a = *(const float4v*)p;
    float4v b = *(const float4v*)(p + 4);
    half8 v;
    v[0]=(_Float16)a[0]; v[1]=(_Float16)a[1]; v[2]=(_Float16)a[2]; v[3]=(_Float16)a[3];
    v[4]=(_Float16)b[0]; v[5]=(_Float16)b[1]; v[6]=(_Float16)b[2]; v[7]=(_Float16)b[3];
    return v;
}

__global__ void cast_f32_f16(const float* __restrict__ in, _Float16* __restrict__ out, int n) {
    int i = blockIdx.x * 256 + threadIdx.x;
    if (i < n) out[i] = (_Float16)in[i];
}

// hseq[l][0] = h0 ; flags = 0
__global__ void init_h(const float* __restrict__ h0, _Float16* __restrict__ hseq,
                       unsigned* __restrict__ flags) {
    int i = blockIdx.x * 256 + threadIdx.x;
    if (i < 256) flags[i] = 0u;
    if (i >= LL * BB * HH) return;
    int l = i / (BB * HH);
    int rest = i - l * (BB * HH);
    hseq[((size_t)l * TSLOTS) * BB * HH + rest] = (_Float16)h0[i];
}

// Reorder w_ih [3H][K] (f32) into MFMA B-fragment order (f16).
__global__ void frag_reorder(const float* __restrict__ src, _Float16* __restrict__ dst,
                             int K, int nks) {
    int idx = blockIdx.x * 256 + threadIdx.x;
    int total = 64 * 3 * nks * 64;
    if (idx >= total) return;
    int lane = idx & 63;
    int r = idx >> 6;
    int ks = r % nks; r /= nks;
    int g = r % 3;
    int jb = r / 3;
    int row = g * HH + jb * 16 + (lane & 15);
    int col = ks * 32 + (lane >> 4) * 8;
    const float* s8 = src + (size_t)row * K + col;
    half8 v;
#pragma unroll
    for (int i = 0; i < 8; ++i) v[i] = (_Float16)s8[i];
    *(half8*)(dst + (size_t)idx * 8) = v;
}

struct PArgs {
    const float* x;              // [T][B][I] f32
    const float* h0;             // [L][B][H] f32
    const _Float16* wih[3];      // frag order; [0]: nks=8, [1,2]: nks=32
    const float* whh_src[3];     // f32 [3H][H] for LDS preload
    const float* bih[3];
    const float* bhh[3];
    _Float16* hseq;              // [L][TSLOTS][B][H] write-once state sequence
    float* out_h;                // d_out + T*B*O
    unsigned* flags;             // [NBLK] per-block monotone superstep flags
};

// Persistent pipelined GRU. 192 blocks x 512 threads (8 waves, 2/SIMD).
// block = (layer = bid>>6, jb = bid&63 -> cols jb*16..+16).
// waves 0-3: recurrent h-side (w_hh fully in LDS), fp32 state in REGISTERS.
// waves 4-7: gi = input-side projection one step ahead.
// Sync: per-wave direct scan of the producer group's 64 flags (1 L3 trip).
__global__ __launch_bounds__(512, 2) void gru_persistent(PArgs a) {
    extern __shared__ __align__(16) char lds[];
    float* giL = (float*)(lds + LDS_GI);
    _Float16* ht = (_Float16*)(lds + LDS_HT);
    const int layer = blockIdx.x >> 6;
    const int jb = blockIdx.x & 63;
    const int tid = threadIdx.x;
    const int lane = tid & 63;
    const int wv = tid >> 6;
    const bool isrec = wv < 4;
    const int lr = lane & 15, lq = lane >> 4;
    const int row0 = (wv & 3) << 4;
    const int j = (jb << 4) + lr;

    const int wih_nks = (layer == 0) ? 8 : 32;
    const _Float16* wih = a.wih[layer] + (size_t)jb * (size_t)(3 * wih_nks * 64 * 8)
                          + (size_t)lane * 8;

    // ---- one-time LDS preload: FULL w_hh slice (96KB), fragment order ----
    {
        const float* wsrc = a.whh_src[layer];
        for (int c = tid; c < 6144; c += 512) {
            int lc = c & 63;
            int ks = (c >> 6) & 31;
            int g  = c >> 11;
            int row = g * HH + (jb << 4) + (lc & 15);
            int col = (ks << 5) + ((lc >> 4) << 3);
            const float* s8 = wsrc + (size_t)row * HH + col;
            half8 v;
#pragma unroll
            for (int i = 0; i < 8; ++i) v[i] = (_Float16)s8[i];
            *(half8*)(lds + (size_t)c * 16) = v;
        }
    }
    __syncthreads();

    const float bir = a.bih[layer][j], biz = a.bih[layer][HH + j], bin = a.bih[layer][2 * HH + j];
    const float bhr = a.bhh[layer][j], bhz = a.bhh[layer][HH + j], bhn = a.bhh[layer][2 * HH + j];
    const char* wb = lds + (size_t)lane * 16;

    // fp32 master state lives in registers: hprev[i2] = h[layer][row0+lq*4+i2][j]
    float hprev[4];
    if (isrec) {
#pragma unroll
        for (int i2 = 0; i2 < 4; ++i2)
            hprev[i2] = a.h0[((size_t)layer * BB + row0 + lq * 4 + i2) * HH + j];
    }

    for (int s = 0; s < SSTEPS; ++s) {
        const int t = s - (2 * layer + 1);             // rec timestep
        const int tp = s - 2 * layer;                  // gi timestep (t+1)
        const bool rec_act = isrec && t >= 0 && t < TT;
        const bool gi_act = !isrec && tp >= 0 && tp < TT;
        const int pr = (s + 1) & 1, pw = s & 1;

        if (rec_act) {
            // wait: own-layer group published h[t] (flag >= s), 1 L3 trip
            for (;;) {
                unsigned f = __hip_atomic_load(&a.flags[layer * 64 + lane],
                                               __ATOMIC_RELAXED, __HIP_MEMORY_SCOPE_AGENT);
                if (__all(f >= (unsigned)s)) break;
                __builtin_amdgcn_s_sleep(1);
            }
            __builtin_amdgcn_sched_barrier(0);

            floatx4 ar{0.f,0.f,0.f,0.f}, az{0.f,0.f,0.f,0.f}, anh{0.f,0.f,0.f,0.f};
            const _Float16* Ah = a.hseq + ((size_t)layer * TSLOTS + t) * BB * HH
                                 + (size_t)(row0 + lr) * HH + lq * 8;
#pragma unroll
            for (int ks = 0; ks < 32; ++ks) {
                half8 av = *(const half8*)(Ah + ks * 32);
                ar  = mfma16(av, *(const half8*)(wb + (0 * 32 + ks) * 1024), ar);
                az  = mfma16(av, *(const half8*)(wb + (1 * 32 + ks) * 1024), az);
                anh = mfma16(av, *(const half8*)(wb + (2 * 32 + ks) * 1024), anh);
            }
            // epilogue: gi from LDS (parity pr), gates, register state update
#pragma unroll
            for (int i2 = 0; i2 < 4; ++i2) {
                int brow = row0 + lq * 4 + i2;
                float gir = giL[((pr * 3 + 0) * 16 + lr) * GI_STRIDE + brow];
                float giz = giL[((pr * 3 + 1) * 16 + lr) * GI_STRIDE + brow];
                float gin = giL[((pr * 3 + 2) * 16 + lr) * GI_STRIDE + brow];
                float rg = fast_sig(ar[i2] + gir + bir + bhr);
                float zg = fast_sig(az[i2] + giz + biz + bhz);
                float ng = fast_tanh(gin + bin + rg * (anh[i2] + bhn));
                float hnew = (1.f - zg) * ng + zg * hprev[i2];
                hprev[i2] = hnew;
                ht[brow * 16 + lr] = (_Float16)hnew;
                if (t == TT - 1) a.out_h[((size_t)layer * BB + brow) * HH + j] = hnew;
            }
        }
        if (gi_act) {
            if (layer > 0) {
                // wait: prev-layer group published y[tp] (flag >= s)
                for (;;) {
                    unsigned f = __hip_atomic_load(&a.flags[(layer - 1) * 64 + lane],
                                                   __ATOMIC_RELAXED, __HIP_MEMORY_SCOPE_AGENT);
                    if (__all(f >= (unsigned)s)) break;
                    __builtin_amdgcn_s_sleep(1);
                }
                __builtin_amdgcn_sched_barrier(0);
            }
            floatx4 g0{0.f,0.f,0.f,0.f}, g1{0.f,0.f,0.f,0.f}, g2{0.f,0.f,0.f,0.f};
            if (layer == 0) {
                const float* Ax = a.x + (size_t)tp * BB * II + (size_t)(row0 + lr) * II + lq * 8;
#pragma unroll
                for (int ks = 0; ks < 8; ++ks) {
                    half8 av = ld_f32x8_cvt(Ax + ks * 32);
                    g0 = mfma16(av, *(const half8*)(wih + (size_t)(0 * 8 + ks) * 512), g0);
                    g1 = mfma16(av, *(const half8*)(wih + (size_t)(1 * 8 + ks) * 512), g1);
                    g2 = mfma16(av, *(const half8*)(wih + (size_t)(2 * 8 + ks) * 512), g2);
                }
            } else {
                const _Float16* Ay = a.hseq + ((size_t)(layer - 1) * TSLOTS + (tp + 1)) * BB * HH
                                     + (size_t)(row0 + lr) * HH + lq * 8;
#pragma unroll
                for (int ks = 0; ks < 32; ++ks) {
                    half8 av = *(const half8*)(Ay + ks * 32);
                    g0 = mfma16(av, *(const half8*)(wih + (size_t)(0 * 32 + ks) * 512), g0);
                    g1 = mfma16(av, *(const half8*)(wih + (size_t)(1 * 32 + ks) * 512), g1);
                    g2 = mfma16(av, *(const half8*)(wih + (size_t)(2 * 32 + ks) * 512), g2);
                }
            }
#pragma unroll
            for (int q = 0; q < 4; ++q) {
                int brow = row0 + lq * 4 + q;
                giL[((pw * 3 + 0) * 16 + lr) * GI_STRIDE + brow] = g0[q];
                giL[((pw * 3 + 1) * 16 + lr) * GI_STRIDE + brow] = g1[q];
                giL[((pw * 3 + 2) * 16 + lr) * GI_STRIDE + brow] = g2[q];
            }
        }
        __syncthreads();   // ht + gi tiles complete

        if (rec_act) {
            // publish 64x16 fp16 tile to hseq[layer][t+1] (agent-scope 8B stores)
            int row = tid >> 2, cg = tid & 3;
            unsigned long long v = *(const unsigned long long*)(ht + row * 16 + cg * 4);
            _Float16* dst = a.hseq + ((size_t)layer * TSLOTS + (t + 1)) * BB * HH
                            + (size_t)row * HH + (jb << 4) + cg * 4;
            __hip_atomic_store((unsigned long long*)dst, v,
                               __ATOMIC_RELAXED, __HIP_MEMORY_SCOPE_AGENT);
        }
        __syncthreads();   // per-wave vmcnt(0) drain: publishes at coherent point
        if (tid == 0)
            __hip_atomic_store(&a.flags[blockIdx.x], (unsigned)(s + 1),
                               __ATOMIC_RELAXED, __HIP_MEMORY_SCOPE_AGENT);
    }
}

// y = hseq[2][t+1] @ fc_w^T + fc_b. M=32768, N=256, K=1024.
__global__ __launch_bounds__(256) void fc_kernel(const _Float16* __restrict__ hseq,
                                                 const _Float16* __restrict__ w,
                                                 const float* __restrict__ bias,
                                                 float* __restrict__ out) {
    const int wid = (blockIdx.x << 2) + (threadIdx.x >> 6);   // 0..4095
    const int lane = threadIdx.x & 63;
    const int mt = wid >> 1;
    const int no = (wid & 1) * 8;
    const int lr = lane & 15, lq = lane >> 4;
    const _Float16* Ar = hseq + ((size_t)2 * TSLOTS * BB + BB + (size_t)(mt * 16 + lr)) * HH
                         + lq * 8;
    floatx4 acc[8] = {};
    for (int k = 0; k < HH; k += 32) {
        half8 av = *(const half8*)(Ar + k);
#pragma unroll
        for (int i = 0; i < 8; ++i) {
            const _Float16* Br = w + (size_t)((no + i) * 16 + lr) * HH + lq * 8 + k;
            acc[i] = mfma16(av, *(const half8*)Br, acc[i]);
        }
    }
#pragma unroll
    for (int i = 0; i < 8; ++i) {
        float b = bias[(no + i) * 16 + lr];
#pragma unroll
        for (int q = 0; q < 4; ++q)
            out[(size_t)(mt * 16 + lq * 4 + q) * OO + (no + i) * 16 + lr] = acc[i][q] + b;
    }
}

extern "C" void kernel_launch(void* const* d_in, const int* in_sizes, int n_in,
                              void* d_out, int out_size, void* d_ws, size_t ws_size,
                              hipStream_t stream) {
    const float* x    = (const float*)d_in[0];
    const float* h0   = (const float*)d_in[1];
    const float* fc_w = (const float*)d_in[2];
    const float* fc_b = (const float*)d_in[3];
    const float* wih[3]; const float* whh[3]; const float* bih[3]; const float* bhh[3];
    for (int l = 0; l < 3; ++l) {
        wih[l] = (const float*)d_in[4 + l * 4 + 0];
        whh[l] = (const float*)d_in[4 + l * 4 + 1];
        bih[l] = (const float*)d_in[4 + l * 4 + 2];
        bhh[l] = (const float*)d_in[4 + l * 4 + 3];
    }

    // ---- carve workspace (~212 MB) ----
    char* p = (char*)d_ws;
    auto alloc = [&](size_t bytes) {
        char* q = p;
        p += (bytes + 255) & ~(size_t)255;
        return q;
    };
    _Float16* hseq = (_Float16*)alloc((size_t)LL * TSLOTS * BB * HH * 2);
    _Float16* wihf[3];
    wihf[0] = (_Float16*)alloc((size_t)3 * HH * II * 2);
    wihf[1] = (_Float16*)alloc((size_t)3 * HH * HH * 2);
    wihf[2] = (_Float16*)alloc((size_t)3 * HH * HH * 2);
    _Float16* fcw16 = (_Float16*)alloc((size_t)OO * HH * 2);
    unsigned* flags = (unsigned*)alloc(1024);
    if ((size_t)(p - (char*)d_ws) > ws_size) return;

    // ---- prep ----
    cast_f32_f16<<<(OO * HH + 255) / 256, 256, 0, stream>>>(fc_w, fcw16, OO * HH);
    frag_reorder<<<384, 256, 0, stream>>>(wih[0], wihf[0], II, 8);
    frag_reorder<<<1536, 256, 0, stream>>>(wih[1], wihf[1], HH, 32);
    frag_reorder<<<1536, 256, 0, stream>>>(wih[2], wihf[2], HH, 32);
    init_h<<<768, 256, 0, stream>>>(h0, hseq, flags);

    // ---- persistent recurrent kernel (plain launch, 124KB dynamic LDS) ----
    PArgs a;
    a.x = x;
    a.h0 = h0;
    for (int l = 0; l < 3; ++l) {
        a.wih[l] = wihf[l];
        a.whh_src[l] = whh[l];
        a.bih[l] = bih[l];
        a.bhh[l] = bhh[l];
    }
    a.hseq = hseq;
    a.out_h = (float*)d_out + (size_t)TT * BB * OO;
    a.flags = flags;

    hipFuncSetAttribute((const void*)gru_persistent,
                        hipFuncAttributeMaxDynamicSharedMemorySize, LDS_TOTAL);
    gru_persistent<<<NBLK, 512, LDS_TOTAL, stream>>>(a);

    // ---- final FC ----
    fc_kernel<<<1024, 256, 0, stream>>>(hseq, fcw16, fc_b, (float*)d_out);
}

// Round 8
// 7857.996 us; speedup vs baseline: 1.2838x; 1.2838x over previous
//
#include <hip/hip_runtime.h>
#include <cstdint>
#include <cstddef>

// GRU: T=512, B=64, I=256, H=1024, O=256, L=3
#define TT 512
#define BB 64
#define II 256
#define HH 1024
#define OO 256
#define LL 3
#define NBLK 192
#define TSLOTS 513            // T+1 state slots per layer
#define SSTEPS 520            // 3-superstep/layer pipeline: rec_l(t) at t+3l+2
// LDS layout (bytes)
#define LDS_GI   98304                 // after 96KB whh frags
#define GI_STRIDE 68                   // floats, padded
#define LDS_HT   (LDS_GI + 26112)      // gi = 2*3*16*68*4 = 26112
#define LDS_TOTAL (LDS_HT + 2048)      // + ht 64*16*2 = 126464

typedef _Float16 half8 __attribute__((ext_vector_type(8)));
typedef float floatx4 __attribute__((ext_vector_type(4)));
typedef float float4v __attribute__((ext_vector_type(4)));

__device__ __forceinline__ floatx4 mfma16(half8 a, half8 b, floatx4 c) {
    return __builtin_amdgcn_mfma_f32_16x16x32_f16(a, b, c, 0, 0, 0);
}

// fast transcendentals: v_exp_f32 + v_rcp_f32 (~1ulp, fine vs fp16 noise)
__device__ __forceinline__ float fast_sig(float x) {
    return __builtin_amdgcn_rcpf(1.f + __builtin_amdgcn_exp2f(-1.44269504f * x));
}
__device__ __forceinline__ float fast_tanh(float x) {
    return 1.f - 2.f * __builtin_amdgcn_rcpf(1.f + __builtin_amdgcn_exp2f(2.88539008f * x));
}

__global__ void cast_f32_f16(const float* __restrict__ in, _Float16* __restrict__ out, int n) {
    int i = blockIdx.x * 256 + threadIdx.x;
    if (i < n) out[i] = (_Float16)in[i];
}

// hseq[l][0] = h0 ; flags = 0
__global__ void init_h(const float* __restrict__ h0, _Float16* __restrict__ hseq,
                       unsigned* __restrict__ flags) {
    int i = blockIdx.x * 256 + threadIdx.x;
    if (i < 256) flags[i] = 0u;
    if (i >= LL * BB * HH) return;
    int l = i / (BB * HH);
    int rest = i - l * (BB * HH);
    hseq[((size_t)l * TSLOTS) * BB * HH + rest] = (_Float16)h0[i];
}

// Reorder w_ih [3H][K] (f32) into MFMA B-fragment order (f16).
__global__ void frag_reorder(const float* __restrict__ src, _Float16* __restrict__ dst,
                             int K, int nks) {
    int idx = blockIdx.x * 256 + threadIdx.x;
    int total = 64 * 3 * nks * 64;
    if (idx >= total) return;
    int lane = idx & 63;
    int r = idx >> 6;
    int ks = r % nks; r /= nks;
    int g = r % 3;
    int jb = r / 3;
    int row = g * HH + jb * 16 + (lane & 15);
    int col = ks * 32 + (lane >> 4) * 8;
    const float* s8 = src + (size_t)row * K + col;
    half8 v;
#pragma unroll
    for (int i = 0; i < 8; ++i) v[i] = (_Float16)s8[i];
    *(half8*)(dst + (size_t)idx * 8) = v;
}

struct PArgs {
    const float* x;              // [T][B][I] f32
    const float* h0;             // [L][B][H] f32
    const _Float16* wih[3];      // frag order; [0]: nks=8, [1,2]: nks=32
    const float* whh_src[3];     // f32 [3H][H] for LDS preload
    const float* bih[3];
    const float* bhh[3];
    _Float16* hseq;              // [L][TSLOTS][B][H] write-once state sequence
    float* out_h;                // d_out + T*B*O
    unsigned* flags;             // [NBLK] per-block monotone superstep flags
};

// Persistent pipelined GRU. 192 blocks x 512 threads (8 waves, 2/SIMD).
// block = (layer = bid>>6, jb = bid&63 -> cols jb*16..+16).
// waves 0-3: rec_l(t) at superstep t+3l+2 (w_hh in LDS, state in registers)
// waves 4-7: gi_l(t) at superstep t+3l+1 (one step of slack vs rec)
__global__ __launch_bounds__(512, 2) void gru_persistent(PArgs a) {
    extern __shared__ __align__(16) char lds[];
    float* giL = (float*)(lds + LDS_GI);
    _Float16* ht = (_Float16*)(lds + LDS_HT);
    const int layer = blockIdx.x >> 6;
    const int jb = blockIdx.x & 63;
    const int tid = threadIdx.x;
    const int lane = tid & 63;
    const int wv = tid >> 6;
    const bool isrec = wv < 4;
    const int lr = lane & 15, lq = lane >> 4;
    const int row0 = (wv & 3) << 4;
    const int j = (jb << 4) + lr;

    const int wih_nks = (layer == 0) ? 8 : 32;
    const _Float16* wih = a.wih[layer] + (size_t)jb * (size_t)(3 * wih_nks * 64 * 8)
                          + (size_t)lane * 8;

    // ---- one-time LDS preload: FULL w_hh slice (96KB), fragment order ----
    {
        const float* wsrc = a.whh_src[layer];
        for (int c = tid; c < 6144; c += 512) {
            int lc = c & 63;
            int ks = (c >> 6) & 31;
            int g  = c >> 11;
            int row = g * HH + (jb << 4) + (lc & 15);
            int col = (ks << 5) + ((lc >> 4) << 3);
            const float* s8 = wsrc + (size_t)row * HH + col;
            half8 v;
#pragma unroll
            for (int i = 0; i < 8; ++i) v[i] = (_Float16)s8[i];
            *(half8*)(lds + (size_t)c * 16) = v;
        }
    }
    __syncthreads();

    const float bir = a.bih[layer][j], biz = a.bih[layer][HH + j], bin = a.bih[layer][2 * HH + j];
    const float bhr = a.bhh[layer][j], bhz = a.bhh[layer][HH + j], bhn = a.bhh[layer][2 * HH + j];
    const char* wb = lds + (size_t)lane * 16;

    // fp32 master state in registers: hprev[i2] = h[layer][row0+lq*4+i2][j]
    float hprev[4];
    if (isrec) {
#pragma unroll
        for (int i2 = 0; i2 < 4; ++i2)
            hprev[i2] = a.h0[((size_t)layer * BB + row0 + lq * 4 + i2) * HH + j];
    }

    for (int s = 0; s < SSTEPS; ++s) {
        const int t  = s - (3 * layer + 2);            // rec timestep
        const int tg = s - (3 * layer + 1);            // gi timestep
        const bool t_valid = (t >= 0 && t < TT);
        const bool rec_act = isrec && t_valid;
        const bool gi_act = !isrec && tg >= 0 && tg < TT;

        if (rec_act) {
            // wait: own-layer group finished superstep s-1 (flag >= s)
            for (;;) {
                unsigned f = __hip_atomic_load(&a.flags[layer * 64 + lane],
                                               __ATOMIC_RELAXED, __HIP_MEMORY_SCOPE_AGENT);
                if (__all(f >= (unsigned)s)) break;
                __builtin_amdgcn_s_sleep(2);
            }
            __builtin_amdgcn_sched_barrier(0);

            floatx4 ar{0.f,0.f,0.f,0.f}, az{0.f,0.f,0.f,0.f}, anh{0.f,0.f,0.f,0.f};
            const _Float16* Ah = a.hseq + ((size_t)layer * TSLOTS + t) * BB * HH
                                 + (size_t)(row0 + lr) * HH + lq * 8;
            // deep-staged K loop: 2 halves x (16 staged loads -> 48 MFMA)
#pragma unroll
            for (int h2 = 0; h2 < 2; ++h2) {
                half8 av[16];
#pragma unroll
                for (int ks = 0; ks < 16; ++ks)
                    av[ks] = *(const half8*)(Ah + (h2 * 16 + ks) * 32);
#pragma unroll
                for (int ks = 0; ks < 16; ++ks) {
                    const int kk = h2 * 16 + ks;
                    ar  = mfma16(av[ks], *(const half8*)(wb + (0 * 32 + kk) * 1024), ar);
                    az  = mfma16(av[ks], *(const half8*)(wb + (1 * 32 + kk) * 1024), az);
                    anh = mfma16(av[ks], *(const half8*)(wb + (2 * 32 + kk) * 1024), anh);
                }
            }
            // epilogue: gi from LDS slot (t&1), gates, register state update
            const int slot = t & 1;
#pragma unroll
            for (int i2 = 0; i2 < 4; ++i2) {
                int brow = row0 + lq * 4 + i2;
                float gir = giL[((slot * 3 + 0) * 16 + lr) * GI_STRIDE + brow];
                float giz = giL[((slot * 3 + 1) * 16 + lr) * GI_STRIDE + brow];
                float gin = giL[((slot * 3 + 2) * 16 + lr) * GI_STRIDE + brow];
                float rg = fast_sig(ar[i2] + gir + bir + bhr);
                float zg = fast_sig(az[i2] + giz + biz + bhz);
                float ng = fast_tanh(gin + bin + rg * (anh[i2] + bhn));
                float hnew = (1.f - zg) * ng + zg * hprev[i2];
                hprev[i2] = hnew;
                ht[brow * 16 + lr] = (_Float16)hnew;
                if (t == TT - 1) a.out_h[((size_t)layer * BB + brow) * HH + j] = hnew;
            }
        }
        if (gi_act) {
            const int slot = tg & 1;
            floatx4 g0{0.f,0.f,0.f,0.f}, g1{0.f,0.f,0.f,0.f}, g2{0.f,0.f,0.f,0.f};
            if (layer == 0) {
                const float* Ax = a.x + (size_t)tg * BB * II + (size_t)(row0 + lr) * II + lq * 8;
                float4v xa[16];
#pragma unroll
                for (int ks = 0; ks < 8; ++ks) {
                    xa[2 * ks]     = *(const float4v*)(Ax + ks * 32);
                    xa[2 * ks + 1] = *(const float4v*)(Ax + ks * 32 + 4);
                }
#pragma unroll
                for (int ks = 0; ks < 8; ++ks) {
                    half8 av;
#pragma unroll
                    for (int e = 0; e < 4; ++e) {
                        av[e]     = (_Float16)xa[2 * ks][e];
                        av[e + 4] = (_Float16)xa[2 * ks + 1][e];
                    }
                    g0 = mfma16(av, *(const half8*)(wih + (size_t)(0 * 8 + ks) * 512), g0);
                    g1 = mfma16(av, *(const half8*)(wih + (size_t)(1 * 8 + ks) * 512), g1);
                    g2 = mfma16(av, *(const half8*)(wih + (size_t)(2 * 8 + ks) * 512), g2);
                }
            } else {
                // wait: prev-layer finished superstep s-2 (flag >= s-1); usually ready
                for (;;) {
                    unsigned f = __hip_atomic_load(&a.flags[(layer - 1) * 64 + lane],
                                                   __ATOMIC_RELAXED, __HIP_MEMORY_SCOPE_AGENT);
                    if (__all(f >= (unsigned)(s - 1))) break;
                    __builtin_amdgcn_s_sleep(2);
                }
                __builtin_amdgcn_sched_barrier(0);
                const _Float16* Ay = a.hseq + ((size_t)(layer - 1) * TSLOTS + (tg + 1)) * BB * HH
                                     + (size_t)(row0 + lr) * HH + lq * 8;
#pragma unroll
                for (int h2 = 0; h2 < 2; ++h2) {
                    half8 av[16];
#pragma unroll
                    for (int ks = 0; ks < 16; ++ks)
                        av[ks] = *(const half8*)(Ay + (h2 * 16 + ks) * 32);
#pragma unroll
                    for (int ks = 0; ks < 16; ++ks) {
                        const int kk = h2 * 16 + ks;
                        g0 = mfma16(av[ks], *(const half8*)(wih + (size_t)(0 * 32 + kk) * 512), g0);
                        g1 = mfma16(av[ks], *(const half8*)(wih + (size_t)(1 * 32 + kk) * 512), g1);
                        g2 = mfma16(av[ks], *(const half8*)(wih + (size_t)(2 * 32 + kk) * 512), g2);
                    }
                }
            }
#pragma unroll
            for (int q = 0; q < 4; ++q) {
                int brow = row0 + lq * 4 + q;
                giL[((slot * 3 + 0) * 16 + lr) * GI_STRIDE + brow] = g0[q];
                giL[((slot * 3 + 1) * 16 + lr) * GI_STRIDE + brow] = g1[q];
                giL[((slot * 3 + 2) * 16 + lr) * GI_STRIDE + brow] = g2[q];
            }
        }
        __syncthreads();   // ht + gi tiles complete

        if (t_valid && tid < 256) {
            // publish 64x16 fp16 tile to hseq[layer][t+1] (agent-scope 8B stores)
            int row = tid >> 2, cg = tid & 3;
            unsigned long long v = *(const unsigned long long*)(ht + row * 16 + cg * 4);
            _Float16* dst = a.hseq + ((size_t)layer * TSLOTS + (t + 1)) * BB * HH
                            + (size_t)row * HH + (jb << 4) + cg * 4;
            __hip_atomic_store((unsigned long long*)dst, v,
                               __ATOMIC_RELAXED, __HIP_MEMORY_SCOPE_AGENT);
        }
        __syncthreads();   // per-wave vmcnt(0) drain: stores at coherent point
        if (tid == 0)
            __hip_atomic_store(&a.flags[blockIdx.x], (unsigned)(s + 1),
                               __ATOMIC_RELAXED, __HIP_MEMORY_SCOPE_AGENT);
    }
}

// y = hseq[2][t+1] @ fc_w^T + fc_b. M=32768, N=256, K=1024.
__global__ __launch_bounds__(256) void fc_kernel(const _Float16* __restrict__ hseq,
                                                 const _Float16* __restrict__ w,
                                                 const float* __restrict__ bias,
                                                 float* __restrict__ out) {
    const int wid = (blockIdx.x << 2) + (threadIdx.x >> 6);   // 0..4095
    const int lane = threadIdx.x & 63;
    const int mt = wid >> 1;
    const int no = (wid & 1) * 8;
    const int lr = lane & 15, lq = lane >> 4;
    const _Float16* Ar = hseq + ((size_t)2 * TSLOTS * BB + BB + (size_t)(mt * 16 + lr)) * HH
                         + lq * 8;
    floatx4 acc[8] = {};
    for (int k = 0; k < HH; k += 32) {
        half8 av = *(const half8*)(Ar + k);
#pragma unroll
        for (int i = 0; i < 8; ++i) {
            const _Float16* Br = w + (size_t)((no + i) * 16 + lr) * HH + lq * 8 + k;
            acc[i] = mfma16(av, *(const half8*)Br, acc[i]);
        }
    }
#pragma unroll
    for (int i = 0; i < 8; ++i) {
        float b = bias[(no + i) * 16 + lr];
#pragma unroll
        for (int q = 0; q < 4; ++q)
            out[(size_t)(mt * 16 + lq * 4 + q) * OO + (no + i) * 16 + lr] = acc[i][q] + b;
    }
}

extern "C" void kernel_launch(void* const* d_in, const int* in_sizes, int n_in,
                              void* d_out, int out_size, void* d_ws, size_t ws_size,
                              hipStream_t stream) {
    const float* x    = (const float*)d_in[0];
    const float* h0   = (const float*)d_in[1];
    const float* fc_w = (const float*)d_in[2];
    const float* fc_b = (const float*)d_in[3];
    const float* wih[3]; const float* whh[3]; const float* bih[3]; const float* bhh[3];
    for (int l = 0; l < 3; ++l) {
        wih[l] = (const float*)d_in[4 + l * 4 + 0];
        whh[l] = (const float*)d_in[4 + l * 4 + 1];
        bih[l] = (const float*)d_in[4 + l * 4 + 2];
        bhh[l] = (const float*)d_in[4 + l * 4 + 3];
    }

    // ---- carve workspace (~212 MB) ----
    char* p = (char*)d_ws;
    auto alloc = [&](size_t bytes) {
        char* q = p;
        p += (bytes + 255) & ~(size_t)255;
        return q;
    };
    _Float16* hseq = (_Float16*)alloc((size_t)LL * TSLOTS * BB * HH * 2);
    _Float16* wihf[3];
    wihf[0] = (_Float16*)alloc((size_t)3 * HH * II * 2);
    wihf[1] = (_Float16*)alloc((size_t)3 * HH * HH * 2);
    wihf[2] = (_Float16*)alloc((size_t)3 * HH * HH * 2);
    _Float16* fcw16 = (_Float16*)alloc((size_t)OO * HH * 2);
    unsigned* flags = (unsigned*)alloc(1024);
    if ((size_t)(p - (char*)d_ws) > ws_size) return;

    // ---- prep ----
    cast_f32_f16<<<(OO * HH + 255) / 256, 256, 0, stream>>>(fc_w, fcw16, OO * HH);
    frag_reorder<<<384, 256, 0, stream>>>(wih[0], wihf[0], II, 8);
    frag_reorder<<<1536, 256, 0, stream>>>(wih[1], wihf[1], HH, 32);
    frag_reorder<<<1536, 256, 0, stream>>>(wih[2], wihf[2], HH, 32);
    init_h<<<768, 256, 0, stream>>>(h0, hseq, flags);

    // ---- persistent recurrent kernel (plain launch, 124KB dynamic LDS) ----
    PArgs a;
    a.x = x;
    a.h0 = h0;
    for (int l = 0; l < 3; ++l) {
        a.wih[l] = wihf[l];
        a.whh_src[l] = whh[l];
        a.bih[l] = bih[l];
        a.bhh[l] = bhh[l];
    }
    a.hseq = hseq;
    a.out_h = (float*)d_out + (size_t)TT * BB * OO;
    a.flags = flags;

    hipFuncSetAttribute((const void*)gru_persistent,
                        hipFuncAttributeMaxDynamicSharedMemorySize, LDS_TOTAL);
    gru_persistent<<<NBLK, 512, LDS_TOTAL, stream>>>(a);

    // ---- final FC ----
    fc_kernel<<<1024, 256, 0, stream>>>(hseq, fcw16, fc_b, (float*)d_out);
}

// Round 9
// 7332.680 us; speedup vs baseline: 1.3758x; 1.0716x over previous
//
#include <hip/hip_runtime.h>
#include <cstdint>
#include <cstddef>

// GRU: T=512, B=64, I=256, H=1024, O=256, L=3
#define TT 512
#define BB 64
#define II 256
#define HH 1024
#define OO 256
#define LL 3
#define NBLK 192
#define TSLOTS 513            // T+1 state slots per layer
#define SSTEPS 520            // 3-superstep/layer pipeline: rec_l(t) at t+3l+2
// LDS layout (bytes)
#define LDS_GI   98304                 // after 96KB whh frags
#define GI_STRIDE 68                   // floats, padded
#define LDS_HT   (LDS_GI + 26112)      // gi = 2*3*16*68*4 = 26112
#define LDS_MB   (LDS_HT + 2048)       // + ht 64*16*2
#define LDS_TOTAL (LDS_MB + 64)        // + mailbox words

typedef _Float16 half8 __attribute__((ext_vector_type(8)));
typedef float floatx4 __attribute__((ext_vector_type(4)));
typedef float float4v __attribute__((ext_vector_type(4)));

__device__ __forceinline__ floatx4 mfma16(half8 a, half8 b, floatx4 c) {
    return __builtin_amdgcn_mfma_f32_16x16x32_f16(a, b, c, 0, 0, 0);
}

// fast transcendentals: v_exp_f32 + v_rcp_f32 (~1ulp, fine vs fp16 noise)
__device__ __forceinline__ float fast_sig(float x) {
    return __builtin_amdgcn_rcpf(1.f + __builtin_amdgcn_exp2f(-1.44269504f * x));
}
__device__ __forceinline__ float fast_tanh(float x) {
    return 1.f - 2.f * __builtin_amdgcn_rcpf(1.f + __builtin_amdgcn_exp2f(2.88539008f * x));
}

__global__ void cast_f32_f16(const float* __restrict__ in, _Float16* __restrict__ out, int n) {
    int i = blockIdx.x * 256 + threadIdx.x;
    if (i < n) out[i] = (_Float16)in[i];
}

// hseq[l][0] = h0 ; flags = 0
__global__ void init_h(const float* __restrict__ h0, _Float16* __restrict__ hseq,
                       unsigned* __restrict__ flags) {
    int i = blockIdx.x * 256 + threadIdx.x;
    if (i < 256) flags[i] = 0u;
    if (i >= LL * BB * HH) return;
    int l = i / (BB * HH);
    int rest = i - l * (BB * HH);
    hseq[((size_t)l * TSLOTS) * BB * HH + rest] = (_Float16)h0[i];
}

// Reorder w_ih [3H][K] (f32) into MFMA B-fragment order (f16).
__global__ void frag_reorder(const float* __restrict__ src, _Float16* __restrict__ dst,
                             int K, int nks) {
    int idx = blockIdx.x * 256 + threadIdx.x;
    int total = 64 * 3 * nks * 64;
    if (idx >= total) return;
    int lane = idx & 63;
    int r = idx >> 6;
    int ks = r % nks; r /= nks;
    int g = r % 3;
    int jb = r / 3;
    int row = g * HH + jb * 16 + (lane & 15);
    int col = ks * 32 + (lane >> 4) * 8;
    const float* s8 = src + (size_t)row * K + col;
    half8 v;
#pragma unroll
    for (int i = 0; i < 8; ++i) v[i] = (_Float16)s8[i];
    *(half8*)(dst + (size_t)idx * 8) = v;
}

struct PArgs {
    const float* x;              // [T][B][I] f32
    const float* h0;             // [L][B][H] f32
    const _Float16* wih[3];      // frag order; [0]: nks=8, [1,2]: nks=32
    const float* whh_src[3];     // f32 [3H][H] for LDS preload
    const float* bih[3];
    const float* bhh[3];
    _Float16* hseq;              // [L][TSLOTS][B][H] write-once state sequence
    float* out_h;                // d_out + T*B*O
    unsigned* flags;             // [NBLK] per-block monotone superstep flags
};

// Persistent pipelined GRU. 192 blocks x 512 threads (8 waves, 2/SIMD).
// block = (layer = bid>>6, jb = bid&63 -> cols jb*16..+16).
// waves 0-3: rec_l(t) at superstep t+3l+2 (w_hh in LDS, state in registers)
// waves 4-7: gi_l(t) at superstep t+3l+1 (one step of slack vs rec)
// Sync: wave0 polls own-layer flags -> LDS mailbox; wave4 polls prev-layer
// flags -> LDS mailbox; all other waves spin on LDS (no fabric traffic).
__global__ __launch_bounds__(512, 2) void gru_persistent(PArgs a) {
    extern __shared__ __align__(16) char lds[];
    float* giL = (float*)(lds + LDS_GI);
    _Float16* ht = (_Float16*)(lds + LDS_HT);
    volatile unsigned* ep_own  = (volatile unsigned*)(lds + LDS_MB);
    volatile unsigned* ep_prev = (volatile unsigned*)(lds + LDS_MB + 4);
    const int layer = blockIdx.x >> 6;
    const int jb = blockIdx.x & 63;
    const int tid = threadIdx.x;
    const int lane = tid & 63;
    const int wv = tid >> 6;
    const bool isrec = wv < 4;
    const int lr = lane & 15, lq = lane >> 4;
    const int row0 = (wv & 3) << 4;
    const int j = (jb << 4) + lr;

    const int wih_nks = (layer == 0) ? 8 : 32;
    const _Float16* wih = a.wih[layer] + (size_t)jb * (size_t)(3 * wih_nks * 64 * 8)
                          + (size_t)lane * 8;

    if (tid == 0) { *ep_own = 0u; *ep_prev = 0u; }

    // ---- one-time LDS preload: FULL w_hh slice (96KB), fragment order ----
    {
        const float* wsrc = a.whh_src[layer];
        for (int c = tid; c < 6144; c += 512) {
            int lc = c & 63;
            int ks = (c >> 6) & 31;
            int g  = c >> 11;
            int row = g * HH + (jb << 4) + (lc & 15);
            int col = (ks << 5) + ((lc >> 4) << 3);
            const float* s8 = wsrc + (size_t)row * HH + col;
            half8 v;
#pragma unroll
            for (int i = 0; i < 8; ++i) v[i] = (_Float16)s8[i];
            *(half8*)(lds + (size_t)c * 16) = v;
        }
    }
    __syncthreads();

    const float bir = a.bih[layer][j], biz = a.bih[layer][HH + j], bin = a.bih[layer][2 * HH + j];
    const float bhr = a.bhh[layer][j], bhz = a.bhh[layer][HH + j], bhn = a.bhh[layer][2 * HH + j];
    const char* wb = lds + (size_t)lane * 16;

    // fp32 master state in registers: hprev[i2] = h[layer][row0+lq*4+i2][j]
    float hprev[4];
    if (isrec) {
#pragma unroll
        for (int i2 = 0; i2 < 4; ++i2)
            hprev[i2] = a.h0[((size_t)layer * BB + row0 + lq * 4 + i2) * HH + j];
    }

    for (int s = 0; s < SSTEPS; ++s) {
        const int t  = s - (3 * layer + 2);            // rec timestep
        const int tg = s - (3 * layer + 1);            // gi timestep
        const bool t_valid = (t >= 0 && t < TT);
        const bool rec_act = isrec && t_valid;
        const bool gi_act = !isrec && tg >= 0 && tg < TT;

        if (rec_act) {
            // wait: own-layer group finished superstep s-1 (flag >= s)
            if (wv == 0) {
                for (;;) {
                    unsigned f = __hip_atomic_load(&a.flags[layer * 64 + lane],
                                                   __ATOMIC_RELAXED, __HIP_MEMORY_SCOPE_AGENT);
                    if (__all(f >= (unsigned)s)) break;
                    __builtin_amdgcn_s_sleep(1);
                }
                if (lane == 0) *ep_own = (unsigned)s;
            } else {
                while (*ep_own < (unsigned)s) __builtin_amdgcn_s_sleep(1);
            }
            __builtin_amdgcn_sched_barrier(0);

            // hoisted gi reads (independent of the MFMA chain)
            const int slot = t & 1;
            float gir[4], giz[4], gin[4];
#pragma unroll
            for (int i2 = 0; i2 < 4; ++i2) {
                int brow = row0 + lq * 4 + i2;
                gir[i2] = giL[((slot * 3 + 0) * 16 + lr) * GI_STRIDE + brow];
                giz[i2] = giL[((slot * 3 + 1) * 16 + lr) * GI_STRIDE + brow];
                gin[i2] = giL[((slot * 3 + 2) * 16 + lr) * GI_STRIDE + brow];
            }

            const _Float16* Ah = a.hseq + ((size_t)layer * TSLOTS + t) * BB * HH
                                 + (size_t)(row0 + lr) * HH + lq * 8;
            // single 32-deep staged batch: one L3 round trip
            half8 av[32];
#pragma unroll
            for (int ks = 0; ks < 32; ++ks)
                av[ks] = *(const half8*)(Ah + ks * 32);
            floatx4 ar{0.f,0.f,0.f,0.f}, az{0.f,0.f,0.f,0.f}, anh{0.f,0.f,0.f,0.f};
#pragma unroll
            for (int ks = 0; ks < 32; ++ks) {
                ar  = mfma16(av[ks], *(const half8*)(wb + (0 * 32 + ks) * 1024), ar);
                az  = mfma16(av[ks], *(const half8*)(wb + (1 * 32 + ks) * 1024), az);
                anh = mfma16(av[ks], *(const half8*)(wb + (2 * 32 + ks) * 1024), anh);
            }
            // epilogue: gates, register state update
#pragma unroll
            for (int i2 = 0; i2 < 4; ++i2) {
                int brow = row0 + lq * 4 + i2;
                float rg = fast_sig(ar[i2] + gir[i2] + bir + bhr);
                float zg = fast_sig(az[i2] + giz[i2] + biz + bhz);
                float ng = fast_tanh(gin[i2] + bin + rg * (anh[i2] + bhn));
                float hnew = (1.f - zg) * ng + zg * hprev[i2];
                hprev[i2] = hnew;
                ht[brow * 16 + lr] = (_Float16)hnew;
            }
            if (t == TT - 1) {
#pragma unroll
                for (int i2 = 0; i2 < 4; ++i2)
                    a.out_h[((size_t)layer * BB + row0 + lq * 4 + i2) * HH + j] = hprev[i2];
            }
        }
        if (gi_act) {
            const int slot = tg & 1;
            floatx4 g0{0.f,0.f,0.f,0.f}, g1{0.f,0.f,0.f,0.f}, g2{0.f,0.f,0.f,0.f};
            if (layer == 0) {
                const float* Ax = a.x + (size_t)tg * BB * II + (size_t)(row0 + lr) * II + lq * 8;
                float4v xa[16];
#pragma unroll
                for (int ks = 0; ks < 8; ++ks) {
                    xa[2 * ks]     = *(const float4v*)(Ax + ks * 32);
                    xa[2 * ks + 1] = *(const float4v*)(Ax + ks * 32 + 4);
                }
#pragma unroll
                for (int ks = 0; ks < 8; ++ks) {
                    half8 av;
#pragma unroll
                    for (int e = 0; e < 4; ++e) {
                        av[e]     = (_Float16)xa[2 * ks][e];
                        av[e + 4] = (_Float16)xa[2 * ks + 1][e];
                    }
                    g0 = mfma16(av, *(const half8*)(wih + (size_t)(0 * 8 + ks) * 512), g0);
                    g1 = mfma16(av, *(const half8*)(wih + (size_t)(1 * 8 + ks) * 512), g1);
                    g2 = mfma16(av, *(const half8*)(wih + (size_t)(2 * 8 + ks) * 512), g2);
                }
            } else {
                // wait: prev-layer finished superstep s-2 (flag >= s-1)
                if (wv == 4) {
                    for (;;) {
                        unsigned f = __hip_atomic_load(&a.flags[(layer - 1) * 64 + lane],
                                                       __ATOMIC_RELAXED, __HIP_MEMORY_SCOPE_AGENT);
                        if (__all(f >= (unsigned)(s - 1))) break;
                        __builtin_amdgcn_s_sleep(1);
                    }
                    if (lane == 0) *ep_prev = (unsigned)s;
                } else {
                    while (*ep_prev < (unsigned)s) __builtin_amdgcn_s_sleep(1);
                }
                __builtin_amdgcn_sched_barrier(0);
                const _Float16* Ay = a.hseq + ((size_t)(layer - 1) * TSLOTS + (tg + 1)) * BB * HH
                                     + (size_t)(row0 + lr) * HH + lq * 8;
                half8 av[32];
#pragma unroll
                for (int ks = 0; ks < 32; ++ks)
                    av[ks] = *(const half8*)(Ay + ks * 32);
#pragma unroll
                for (int ks = 0; ks < 32; ++ks) {
                    g0 = mfma16(av[ks], *(const half8*)(wih + (size_t)(0 * 32 + ks) * 512), g0);
                    g1 = mfma16(av[ks], *(const half8*)(wih + (size_t)(1 * 32 + ks) * 512), g1);
                    g2 = mfma16(av[ks], *(const half8*)(wih + (size_t)(2 * 32 + ks) * 512), g2);
                }
            }
#pragma unroll
            for (int q = 0; q < 4; ++q) {
                int brow = row0 + lq * 4 + q;
                giL[((slot * 3 + 0) * 16 + lr) * GI_STRIDE + brow] = g0[q];
                giL[((slot * 3 + 1) * 16 + lr) * GI_STRIDE + brow] = g1[q];
                giL[((slot * 3 + 2) * 16 + lr) * GI_STRIDE + brow] = g2[q];
            }
        }
        __syncthreads();   // ht + gi tiles complete

        if (t_valid && tid < 256) {
            // publish 64x16 fp16 tile to hseq[layer][t+1] (agent-scope 8B stores)
            int row = tid >> 2, cg = tid & 3;
            unsigned long long v = *(const unsigned long long*)(ht + row * 16 + cg * 4);
            _Float16* dst = a.hseq + ((size_t)layer * TSLOTS + (t + 1)) * BB * HH
                            + (size_t)row * HH + (jb << 4) + cg * 4;
            __hip_atomic_store((unsigned long long*)dst, v,
                               __ATOMIC_RELAXED, __HIP_MEMORY_SCOPE_AGENT);
        }
        __syncthreads();   // vmcnt(0) drain: stores at coherent point
        if (tid == 0)
            __hip_atomic_store(&a.flags[blockIdx.x], (unsigned)(s + 1),
                               __ATOMIC_RELAXED, __HIP_MEMORY_SCOPE_AGENT);
    }
}

// y = hseq[2][t+1] @ fc_w^T + fc_b. M=32768, N=256, K=1024.
__global__ __launch_bounds__(256) void fc_kernel(const _Float16* __restrict__ hseq,
                                                 const _Float16* __restrict__ w,
                                                 const float* __restrict__ bias,
                                                 float* __restrict__ out) {
    const int wid = (blockIdx.x << 2) + (threadIdx.x >> 6);   // 0..4095
    const int lane = threadIdx.x & 63;
    const int mt = wid >> 1;
    const int no = (wid & 1) * 8;
    const int lr = lane & 15, lq = lane >> 4;
    const _Float16* Ar = hseq + ((size_t)2 * TSLOTS * BB + BB + (size_t)(mt * 16 + lr)) * HH
                         + lq * 8;
    floatx4 acc[8] = {};
    for (int k = 0; k < HH; k += 32) {
        half8 av = *(const half8*)(Ar + k);
#pragma unroll
        for (int i = 0; i < 8; ++i) {
            const _Float16* Br = w + (size_t)((no + i) * 16 + lr) * HH + lq * 8 + k;
            acc[i] = mfma16(av, *(const half8*)Br, acc[i]);
        }
    }
#pragma unroll
    for (int i = 0; i < 8; ++i) {
        float b = bias[(no + i) * 16 + lr];
#pragma unroll
        for (int q = 0; q < 4; ++q)
            out[(size_t)(mt * 16 + lq * 4 + q) * OO + (no + i) * 16 + lr] = acc[i][q] + b;
    }
}

extern "C" void kernel_launch(void* const* d_in, const int* in_sizes, int n_in,
                              void* d_out, int out_size, void* d_ws, size_t ws_size,
                              hipStream_t stream) {
    const float* x    = (const float*)d_in[0];
    const float* h0   = (const float*)d_in[1];
    const float* fc_w = (const float*)d_in[2];
    const float* fc_b = (const float*)d_in[3];
    const float* wih[3]; const float* whh[3]; const float* bih[3]; const float* bhh[3];
    for (int l = 0; l < 3; ++l) {
        wih[l] = (const float*)d_in[4 + l * 4 + 0];
        whh[l] = (const float*)d_in[4 + l * 4 + 1];
        bih[l] = (const float*)d_in[4 + l * 4 + 2];
        bhh[l] = (const float*)d_in[4 + l * 4 + 3];
    }

    // ---- carve workspace (~212 MB) ----
    char* p = (char*)d_ws;
    auto alloc = [&](size_t bytes) {
        char* q = p;
        p += (bytes + 255) & ~(size_t)255;
        return q;
    };
    _Float16* hseq = (_Float16*)alloc((size_t)LL * TSLOTS * BB * HH * 2);
    _Float16* wihf[3];
    wihf[0] = (_Float16*)alloc((size_t)3 * HH * II * 2);
    wihf[1] = (_Float16*)alloc((size_t)3 * HH * HH * 2);
    wihf[2] = (_Float16*)alloc((size_t)3 * HH * HH * 2);
    _Float16* fcw16 = (_Float16*)alloc((size_t)OO * HH * 2);
    unsigned* flags = (unsigned*)alloc(1024);
    if ((size_t)(p - (char*)d_ws) > ws_size) return;

    // ---- prep ----
    cast_f32_f16<<<(OO * HH + 255) / 256, 256, 0, stream>>>(fc_w, fcw16, OO * HH);
    frag_reorder<<<384, 256, 0, stream>>>(wih[0], wihf[0], II, 8);
    frag_reorder<<<1536, 256, 0, stream>>>(wih[1], wihf[1], HH, 32);
    frag_reorder<<<1536, 256, 0, stream>>>(wih[2], wihf[2], HH, 32);
    init_h<<<768, 256, 0, stream>>>(h0, hseq, flags);

    // ---- persistent recurrent kernel (plain launch, ~124KB dynamic LDS) ----
    PArgs a;
    a.x = x;
    a.h0 = h0;
    for (int l = 0; l < 3; ++l) {
        a.wih[l] = wihf[l];
        a.whh_src[l] = whh[l];
        a.bih[l] = bih[l];
        a.bhh[l] = bhh[l];
    }
    a.hseq = hseq;
    a.out_h = (float*)d_out + (size_t)TT * BB * OO;
    a.flags = flags;

    hipFuncSetAttribute((const void*)gru_persistent,
                        hipFuncAttributeMaxDynamicSharedMemorySize, LDS_TOTAL);
    gru_persistent<<<NBLK, 512, LDS_TOTAL, stream>>>(a);

    // ---- final FC ----
    fc_kernel<<<1024, 256, 0, stream>>>(hseq, fcw16, fc_b, (float*)d_out);
}